// Round 3
// baseline (22378.662 us; speedup 1.0000x reference)
//
#include <hip/hip_runtime.h>
#include <hip/hip_bf16.h>
#include <math.h>

typedef unsigned int u32;
typedef unsigned short u16;

// ---------- bf16 helpers ----------
__device__ __forceinline__ float bfbits(u32 hi) { union { u32 u; float f; } v; v.u = hi; return v.f; }
__device__ __forceinline__ float lo16(u32 p) { return bfbits(p << 16); }
__device__ __forceinline__ float hi16(u32 p) { return bfbits(p & 0xffff0000u); }
__device__ __forceinline__ float b2f(u16 x) { return bfbits(((u32)x) << 16); }
__device__ __forceinline__ u16 f2b(float f) {
    union { float f; u32 u; } v; v.f = f;
    u32 u = v.u;
    u32 r = (u + 0x7fffu + ((u >> 16) & 1u)) >> 16;  // RNE
    return (u16)r;
}
__device__ __forceinline__ float cvtf(float x) { return x; }
__device__ __forceinline__ float cvtf(u16 x) { return b2f(x); }
__device__ __forceinline__ void storef(float* p, float v) { *p = v; }
__device__ __forceinline__ void storef(u16* p, float v) { *p = f2b(v); }
__device__ __forceinline__ float sigf(float x) { return 1.f / (1.f + expf(-x)); }
// dot of 8 bf16 (packed in uint4) with 8 floats
__device__ __forceinline__ float dot8(uint4 q, const float* h) {
    return lo16(q.x) * h[0] + hi16(q.x) * h[1] + lo16(q.y) * h[2] + hi16(q.y) * h[3]
         + lo16(q.z) * h[4] + hi16(q.z) * h[5] + lo16(q.w) * h[6] + hi16(q.w) * h[7];
}

// ---------- dtype-world detector ----------
// If the external float tensors are f32 and we interpret their u16 halves as
// bf16, random mantissa halves decode to huge/NaN values. In bf16-world all
// src_emb values are ~N(0,0.05) -> |x| < 1. Writes flag=1 for f32-world.
__global__ void k_detect(const void* __restrict__ emb, int* __restrict__ flag) {
    __shared__ int s;
    if (threadIdx.x == 0) s = 0;
    __syncthreads();
    const u16* p = (const u16*)emb;
    int bad = 0;
    for (int i = threadIdx.x; i < 8192; i += 256) {
        float v = b2f(p[i]);
        if (!(fabsf(v) < 1e4f)) bad = 1;  // catches NaN too
    }
    if (bad) s = 1;
    __syncthreads();
    if (threadIdx.x == 0) *flag = s;
}

// ---------- weight canonicalizer: external (f32 or bf16) -> internal bf16 ----------
__global__ void k_conv(const void* __restrict__ src, u16* __restrict__ dst, int n,
                       const int* __restrict__ flag) {
    int i = blockIdx.x * 256 + threadIdx.x;
    if (i >= n) return;
    if (*flag) dst[i] = f2b(((const float*)src)[i]);
    else       dst[i] = ((const u16*)src)[i];
}

// ---------- embedding gather -> internal bf16 ----------
__global__ void k_embed(const int* __restrict__ tok, const void* __restrict__ emb,
                        u16* __restrict__ out, const int* __restrict__ flag) {
    int row = blockIdx.x;
    int e = threadIdx.x;
    int v = tok[row];
    u16 r;
    if (*flag) r = f2b(((const float*)emb)[(size_t)v * 256 + e]);
    else       r = ((const u16*)emb)[(size_t)v * 256 + e];
    out[(size_t)row * 256 + e] = r;
}

// ---------- generic GEMM: C[m][n] = sum_k A[m][k]*B[n][k] (+bias[n]) ----------
// A: TA (f32 or internal bf16), B: internal bf16 [N][ldb], C: TC
template <typename TA, typename TC>
__global__ __launch_bounds__(256) void k_gemm_nt(
    const TA* __restrict__ A, int lda,
    const u16* __restrict__ B, int ldb,
    const u16* __restrict__ bias,
    TC* __restrict__ C, int ldc,
    int M, int N, int K) {
    __shared__ float As[32][68];
    __shared__ float Bs[32][68];
    const int bm = blockIdx.y * 64, bn = blockIdx.x * 64;
    const int tid = threadIdx.x;
    const int tm = (tid & 15) * 4, tn = (tid >> 4) * 4;
    float acc[4][4] = {};
    const int ml = tid >> 2, kl = (tid & 3) * 8;
    for (int k0 = 0; k0 < K; k0 += 32) {
        {
            float v[8];
            if (bm + ml < M) {
                const TA* ap = A + (size_t)(bm + ml) * lda + (k0 + kl);
#pragma unroll
                for (int i = 0; i < 8; i++) v[i] = cvtf(ap[i]);
            } else {
#pragma unroll
                for (int i = 0; i < 8; i++) v[i] = 0.f;
            }
#pragma unroll
            for (int i = 0; i < 8; i++) As[kl + i][ml] = v[i];
        }
        {
            float v[8];
            if (bn + ml < N) {
                const u16* bp = B + (size_t)(bn + ml) * ldb + (k0 + kl);
#pragma unroll
                for (int i = 0; i < 8; i++) v[i] = b2f(bp[i]);
            } else {
#pragma unroll
                for (int i = 0; i < 8; i++) v[i] = 0.f;
            }
#pragma unroll
            for (int i = 0; i < 8; i++) Bs[kl + i][ml] = v[i];
        }
        __syncthreads();
#pragma unroll
        for (int k = 0; k < 32; k++) {
            float4 av = *(const float4*)&As[k][tm];
            float4 bv = *(const float4*)&Bs[k][tn];
            acc[0][0] += av.x * bv.x; acc[0][1] += av.x * bv.y; acc[0][2] += av.x * bv.z; acc[0][3] += av.x * bv.w;
            acc[1][0] += av.y * bv.x; acc[1][1] += av.y * bv.y; acc[1][2] += av.y * bv.z; acc[1][3] += av.y * bv.w;
            acc[2][0] += av.z * bv.x; acc[2][1] += av.z * bv.y; acc[2][2] += av.z * bv.z; acc[2][3] += av.z * bv.w;
            acc[3][0] += av.w * bv.x; acc[3][1] += av.w * bv.y; acc[3][2] += av.w * bv.z; acc[3][3] += av.w * bv.w;
        }
        __syncthreads();
    }
#pragma unroll
    for (int i = 0; i < 4; i++) {
        int m = bm + tm + i;
        if (m >= M) continue;
#pragma unroll
        for (int j = 0; j < 4; j++) {
            int n = bn + tn + j;
            float v = acc[i][j];
            if (bias) v += b2f(bias[n]);
            storef(&C[(size_t)m * ldc + n], v);
        }
    }
}

// ---------- encoder step (both directions in one launch) ----------
__global__ __launch_bounds__(256) void k_enc_step(
    int t,
    const float* __restrict__ Xf, const float* __restrict__ Xb,
    const u16* __restrict__ Whh_f, const u16* __restrict__ Whh_b,
    float* __restrict__ hbuf, float* __restrict__ cbuf,
    u16* __restrict__ enc) {
    const int d = blockIdx.x >> 5, b = blockIdx.x & 31;
    const int j = threadIdx.x;
    __shared__ float hs[256];
    float* hrow = hbuf + ((size_t)d * 32 + b) * 256;
    float* crow = cbuf + ((size_t)d * 32 + b) * 256;
    hs[j] = (t == 0) ? 0.f : hrow[j];
    float cprev = (t == 0) ? 0.f : crow[j];
    __syncthreads();
    const int pos = (d == 0) ? t : (511 - t);
    const float* xpre = (d == 0 ? Xf : Xb) + ((size_t)pos * 32 + b) * 1024;
    const u16* W = (d == 0) ? Whh_f : Whh_b;
    float a0 = xpre[j], a1 = xpre[256 + j], a2 = xpre[512 + j], a3 = xpre[768 + j];
    const uint4* w0 = (const uint4*)(W + (size_t)j * 256);
    const uint4* w1 = (const uint4*)(W + (size_t)(256 + j) * 256);
    const uint4* w2 = (const uint4*)(W + (size_t)(512 + j) * 256);
    const uint4* w3 = (const uint4*)(W + (size_t)(768 + j) * 256);
#pragma unroll 4
    for (int kk = 0; kk < 32; kk++) {
        const float* hp = &hs[kk * 8];
        a0 += dot8(w0[kk], hp);
        a1 += dot8(w1[kk], hp);
        a2 += dot8(w2[kk], hp);
        a3 += dot8(w3[kk], hp);
    }
    float ig = sigf(a0), fg = sigf(a1), gg = tanhf(a2), og = sigf(a3);
    float c = fg * cprev + ig * gg;
    float h = og * tanhf(c);
    hrow[j] = h;
    crow[j] = c;
    enc[((size_t)b * 512 + pos) * 512 + d * 256 + j] = f2b(h);
}

// ---------- concat final hiddens ----------
__global__ void k_concat_h(const float* __restrict__ hbuf, float* __restrict__ hFB) {
    int b = blockIdx.x, k = threadIdx.x;  // 512 threads
    float v = (k < 256) ? hbuf[(size_t)b * 256 + k] : hbuf[(size_t)(32 + b) * 256 + (k - 256)];
    hFB[(size_t)b * 512 + k] = v;
}

// ---------- decoder LSTM step ----------
__global__ __launch_bounds__(256) void k_dec_a(
    int s,
    const float* __restrict__ Ypart,
    const u16* __restrict__ Whh_d, const u16* __restrict__ Wih_d,
    const float* __restrict__ ht0, const float* __restrict__ ct0,
    float* __restrict__ hdec, float* __restrict__ cdec,
    const float* __restrict__ oprev) {
    const int b = blockIdx.x, j = threadIdx.x;
    __shared__ float hs[256], os[256];
    hs[j] = (s == 0) ? ht0[(size_t)b * 256 + j] : hdec[(size_t)b * 256 + j];
    os[j] = (s == 0) ? 0.f : oprev[(size_t)b * 256 + j];
    float cprev = (s == 0) ? ct0[(size_t)b * 256 + j] : cdec[(size_t)b * 256 + j];
    __syncthreads();
    const float* yp = Ypart + ((size_t)s * 32 + b) * 1024;
    float acc[4] = {yp[j], yp[256 + j], yp[512 + j], yp[768 + j]};
#pragma unroll
    for (int g = 0; g < 4; g++) {
        const uint4* wh = (const uint4*)(Whh_d + (size_t)(g * 256 + j) * 256);
        const uint4* wo = (const uint4*)(Wih_d + (size_t)(g * 256 + j) * 512 + 256);
        float a = 0.f;
#pragma unroll 4
        for (int kk = 0; kk < 32; kk++) {
            a += dot8(wh[kk], &hs[kk * 8]);
            a += dot8(wo[kk], &os[kk * 8]);
        }
        acc[g] += a;
    }
    float ig = sigf(acc[0]), fg = sigf(acc[1]), gg = tanhf(acc[2]), og = sigf(acc[3]);
    float c = fg * cprev + ig * gg;
    float h = og * tanhf(c);
    hdec[(size_t)b * 256 + j] = h;
    cdec[(size_t)b * 256 + j] = c;
}

// ---------- decoder attention + combine ----------
__global__ __launch_bounds__(256) void k_dec_b(
    int s,
    const float* __restrict__ hdec,
    const u16* __restrict__ proj, const u16* __restrict__ enc,
    const u16* __restrict__ Wcomb,
    float* __restrict__ oprev, float* __restrict__ hid) {
    const int b = blockIdx.x, tid = threadIdx.x;
    __shared__ float hs[256];
    __shared__ float ev[512];
    __shared__ float cx[512];
    __shared__ float red[16];
    hs[tid] = hdec[(size_t)b * 256 + tid];
    __syncthreads();
#pragma unroll
    for (int half = 0; half < 2; half++) {
        int s2 = half * 256 + tid;
        const uint4* pr = (const uint4*)(proj + ((size_t)b * 512 + s2) * 256);
        float a = 0.f;
#pragma unroll 4
        for (int kk = 0; kk < 32; kk++) a += dot8(pr[kk], &hs[kk * 8]);
        ev[s2] = a;
    }
    __syncthreads();
    float m = fmaxf(ev[tid], ev[tid + 256]);
    for (int off = 32; off; off >>= 1) m = fmaxf(m, __shfl_down(m, off));
    if ((tid & 63) == 0) red[tid >> 6] = m;
    __syncthreads();
    if (tid == 0) red[8] = fmaxf(fmaxf(red[0], red[1]), fmaxf(red[2], red[3]));
    __syncthreads();
    float mx = red[8];
    float e0 = expf(ev[tid] - mx), e1 = expf(ev[tid + 256] - mx);
    float ss = e0 + e1;
    for (int off = 32; off; off >>= 1) ss += __shfl_down(ss, off);
    if ((tid & 63) == 0) red[4 + (tid >> 6)] = ss;
    __syncthreads();
    if (tid == 0) red[9] = red[4] + red[5] + red[6] + red[7];
    __syncthreads();
    float inv = 1.f / red[9];
    ev[tid] = e0 * inv;
    ev[tid + 256] = e1 * inv;
    __syncthreads();
    {
        float a0 = 0.f, a1 = 0.f;
        const u16* eb = enc + (size_t)b * 512 * 512 + 2 * tid;
#pragma unroll 4
        for (int s2 = 0; s2 < 512; s2++) {
            float w = ev[s2];
            u32 q = *(const u32*)(eb + (size_t)s2 * 512);
            a0 += w * lo16(q);
            a1 += w * hi16(q);
        }
        cx[2 * tid] = a0;
        cx[2 * tid + 1] = a1;
    }
    __syncthreads();
    {
        const uint4* wc = (const uint4*)(Wcomb + (size_t)tid * 768);
        float a = 0.f;
#pragma unroll 4
        for (int kk = 0; kk < 32; kk++) a += dot8(wc[kk], &hs[kk * 8]);
#pragma unroll 4
        for (int kk = 32; kk < 96; kk++) a += dot8(wc[kk], &cx[kk * 8 - 256]);
        float o = tanhf(a);
        oprev[(size_t)b * 256 + tid] = o;
        hid[((size_t)s * 32 + b) * 256 + tid] = o;
    }
}

// ---------- logit at target index: one wave per (t,b) ----------
__global__ __launch_bounds__(256) void k_lidx(
    const int* __restrict__ target, const float* __restrict__ hid,
    const void* __restrict__ WvocV, float* __restrict__ lidx,
    const int* __restrict__ flag) {
    int p = blockIdx.x * 4 + (threadIdx.x >> 6);
    if (p >= 127 * 32) return;
    int lane = threadIdx.x & 63;
    int t = p >> 5, b = p & 31;
    int idx = target[(t + 1) * 32 + b];
    const float* h = hid + (size_t)p * 256;
    const bool f32w = (*flag != 0);
    float a = 0.f;
#pragma unroll
    for (int i = 0; i < 4; i++) {
        int k = lane * 4 + i;
        float wv = f32w ? ((const float*)WvocV)[(size_t)idx * 256 + k]
                        : b2f(((const u16*)WvocV)[(size_t)idx * 256 + k]);
        a += h[k] * wv;
    }
    for (int off = 32; off; off >>= 1) a += __shfl_down(a, off);
    if (lane == 0) lidx[p] = a;
}

// ---------- fused vocab GEMM + sum(exp(logit)) via atomics ----------
__global__ __launch_bounds__(256) void k_sumexp(
    const float* __restrict__ hid, const void* __restrict__ WvocV,
    float* __restrict__ psum, const int* __restrict__ flag) {
    const int t = blockIdx.y;
    const int cb = blockIdx.x * 128;
    const int tid = threadIdx.x;
    const bool f32w = (*flag != 0);
    __shared__ float Hsh[32][260];
    __shared__ float Wsh[32][132];
    __shared__ float red[32][33];
    {
        int r = tid >> 3, kb = (tid & 7) * 32;
        const float4* hp4 = (const float4*)(hid + ((size_t)t * 32 + r) * 256 + kb);
        float4* dst = (float4*)&Hsh[r][kb];
#pragma unroll
        for (int i = 0; i < 8; i++) dst[i] = hp4[i];
    }
    const int rt = tid >> 5, ct = tid & 31;
    float acc[4][4] = {};
    for (int kc = 0; kc < 8; kc++) {
        __syncthreads();
        {
            int c = tid >> 1, half = tid & 1;
            int k0 = half * 16;
            float w[16];
            if (f32w) {
                const float4* wf = (const float4*)((const float*)WvocV + (size_t)(cb + c) * 256 + kc * 32 + half * 16);
                float4 a0 = wf[0], a1 = wf[1], a2 = wf[2], a3 = wf[3];
                w[0] = a0.x; w[1] = a0.y; w[2] = a0.z; w[3] = a0.w;
                w[4] = a1.x; w[5] = a1.y; w[6] = a1.z; w[7] = a1.w;
                w[8] = a2.x; w[9] = a2.y; w[10] = a2.z; w[11] = a2.w;
                w[12] = a3.x; w[13] = a3.y; w[14] = a3.z; w[15] = a3.w;
            } else {
                const uint4* w4 = (const uint4*)((const u16*)WvocV + (size_t)(cb + c) * 256 + kc * 32 + half * 16);
                uint4 q0 = w4[0], q1 = w4[1];
                w[0] = lo16(q0.x); w[1] = hi16(q0.x); w[2] = lo16(q0.y); w[3] = hi16(q0.y);
                w[4] = lo16(q0.z); w[5] = hi16(q0.z); w[6] = lo16(q0.w); w[7] = hi16(q0.w);
                w[8] = lo16(q1.x); w[9] = hi16(q1.x); w[10] = lo16(q1.y); w[11] = hi16(q1.y);
                w[12] = lo16(q1.z); w[13] = hi16(q1.z); w[14] = lo16(q1.w); w[15] = hi16(q1.w);
            }
#pragma unroll
            for (int i = 0; i < 16; i++) Wsh[k0 + i][c] = w[i];
        }
        __syncthreads();
#pragma unroll
        for (int k = 0; k < 32; k++) {
            float4 bv = *(const float4*)&Wsh[k][ct * 4];
            float a0 = Hsh[rt * 4 + 0][kc * 32 + k];
            float a1 = Hsh[rt * 4 + 1][kc * 32 + k];
            float a2 = Hsh[rt * 4 + 2][kc * 32 + k];
            float a3 = Hsh[rt * 4 + 3][kc * 32 + k];
            acc[0][0] += a0 * bv.x; acc[0][1] += a0 * bv.y; acc[0][2] += a0 * bv.z; acc[0][3] += a0 * bv.w;
            acc[1][0] += a1 * bv.x; acc[1][1] += a1 * bv.y; acc[1][2] += a1 * bv.z; acc[1][3] += a1 * bv.w;
            acc[2][0] += a2 * bv.x; acc[2][1] += a2 * bv.y; acc[2][2] += a2 * bv.z; acc[2][3] += a2 * bv.w;
            acc[3][0] += a3 * bv.x; acc[3][1] += a3 * bv.y; acc[3][2] += a3 * bv.z; acc[3][3] += a3 * bv.w;
        }
    }
#pragma unroll
    for (int i = 0; i < 4; i++) {
        float s = expf(acc[i][0]) + expf(acc[i][1]) + expf(acc[i][2]) + expf(acc[i][3]);
        red[rt * 4 + i][ct] = s;
    }
    __syncthreads();
    if (tid < 32) {
        float s = 0.f;
#pragma unroll 8
        for (int c = 0; c < 32; c++) s += red[tid][c];
        atomicAdd(&psum[(size_t)t * 32 + tid], s);
    }
}

// ---------- final scores ----------
__global__ void k_scores(const int* __restrict__ target, const float* __restrict__ lidx,
                         const float* __restrict__ psum, void* __restrict__ outv,
                         const int* __restrict__ flag) {
    int b = threadIdx.x;
    if (b >= 32) return;
    float acc = 0.f;
    for (int t = 0; t < 127; t++) {
        int idx = target[(t + 1) * 32 + b];
        if (idx != 0) {
            int row = t * 32 + b;
            acc += lidx[row] - logf(psum[row]);
        }
    }
    if (*flag) ((float*)outv)[b] = acc;
    else       ((u16*)outv)[b] = f2b(acc);
}

extern "C" void kernel_launch(void* const* d_in, const int* in_sizes, int n_in,
                              void* d_out, int out_size, void* d_ws, size_t ws_size,
                              hipStream_t stream) {
    const int* source = (const int*)d_in[0];
    const int* target = (const int*)d_in[1];
    const void* src_emb = d_in[2];
    const void* tgt_emb = d_in[3];
    const void* Wih_f = d_in[4];
    const void* Whh_f = d_in[5];
    const void* b_f = d_in[6];
    const void* Wih_b = d_in[7];
    const void* Whh_b = d_in[8];
    const void* b_b = d_in[9];
    const void* Wih_d = d_in[10];
    const void* Whh_d = d_in[11];
    const void* b_d = d_in[12];
    const void* Wh = d_in[13];
    const void* Wc = d_in[14];
    const void* Watt = d_in[15];
    const void* Wcomb = d_in[16];
    const void* Wvoc = d_in[17];

    // ---- workspace layout: [flag pad 64 floats][f32 buffers][u16 buffers] ----
    int* flag = (int*)d_ws;
    float* fw = (float*)d_ws;
    size_t off = 64;
    float* Xf = fw + off;     off += (size_t)512 * 32 * 1024;
    float* Xb = fw + off;     off += (size_t)512 * 32 * 1024;
    float* Ypart = fw + off;  off += (size_t)127 * 32 * 1024;
    float* hid = fw + off;    off += (size_t)127 * 32 * 256;
    float* hbuf = fw + off;   off += (size_t)2 * 32 * 256;
    float* cbuf = fw + off;   off += (size_t)2 * 32 * 256;
    float* hFB = fw + off;    off += (size_t)32 * 512;
    float* ht0 = fw + off;    off += (size_t)32 * 256;
    float* ct0 = fw + off;    off += (size_t)32 * 256;
    float* hdec = fw + off;   off += (size_t)32 * 256;
    float* cdec = fw + off;   off += (size_t)32 * 256;
    float* oprev = fw + off;  off += (size_t)32 * 256;
    float* lidx = fw + off;   off += 4096;
    float* psum = fw + off;   off += 4096;
    u16* ub = (u16*)(fw + off);
    size_t uo = 0;
    u16* X = ub + uo;       uo += (size_t)512 * 32 * 256;
    u16* Yemb = ub + uo;    uo += (size_t)127 * 32 * 256;
    u16* enc_p = ub + uo;   uo += (size_t)32 * 512 * 512;
    u16* proj = ub + uo;    uo += (size_t)32 * 512 * 256;
    u16* cWih_f = ub + uo;  uo += 262144;
    u16* cWhh_f = ub + uo;  uo += 262144;
    u16* cb_f = ub + uo;    uo += 1024;
    u16* cWih_b = ub + uo;  uo += 262144;
    u16* cWhh_b = ub + uo;  uo += 262144;
    u16* cb_b = ub + uo;    uo += 1024;
    u16* cWih_d = ub + uo;  uo += 524288;
    u16* cWhh_d = ub + uo;  uo += 262144;
    u16* cb_d = ub + uo;    uo += 1024;
    u16* cWh = ub + uo;     uo += 131072;
    u16* cWc = ub + uo;     uo += 131072;
    u16* cWatt = ub + uo;   uo += 131072;
    u16* cWcomb = ub + uo;  uo += 196608;
    size_t needed = off * 4 + uo * 2;
    if (ws_size < needed) return;  // leaves output zero -> distinct failure signature

    // 0. detect dtype world, canonicalize weights to internal bf16
    k_detect<<<1, 256, 0, stream>>>(src_emb, flag);
    auto conv = [&](const void* s, u16* d, int n) {
        k_conv<<<(n + 255) / 256, 256, 0, stream>>>(s, d, n, flag);
    };
    conv(Wih_f, cWih_f, 262144);  conv(Whh_f, cWhh_f, 262144);  conv(b_f, cb_f, 1024);
    conv(Wih_b, cWih_b, 262144);  conv(Whh_b, cWhh_b, 262144);  conv(b_b, cb_b, 1024);
    conv(Wih_d, cWih_d, 524288);  conv(Whh_d, cWhh_d, 262144);  conv(b_d, cb_d, 1024);
    conv(Wh, cWh, 131072);        conv(Wc, cWc, 131072);
    conv(Watt, cWatt, 131072);    conv(Wcomb, cWcomb, 196608);

    // 1. embed source (internal bf16)
    k_embed<<<512 * 32, 256, 0, stream>>>(source, src_emb, X, flag);
    // 2. x-part gate preactivations for both encoder directions
    k_gemm_nt<u16, float><<<dim3(16, 256), 256, 0, stream>>>(X, 256, cWih_f, 256, cb_f, Xf, 1024, 16384, 1024, 256);
    k_gemm_nt<u16, float><<<dim3(16, 256), 256, 0, stream>>>(X, 256, cWih_b, 256, cb_b, Xb, 1024, 16384, 1024, 256);
    // 3. encoder recurrence (fwd + bwd fused per step)
    for (int t = 0; t < 512; t++)
        k_enc_step<<<64, 256, 0, stream>>>(t, Xf, Xb, cWhh_f, cWhh_b, hbuf, cbuf, enc_p);
    // 4. initial decoder state
    k_concat_h<<<32, 512, 0, stream>>>(hbuf, hFB);
    k_gemm_nt<float, float><<<dim3(4, 1), 256, 0, stream>>>(hFB, 512, cWh, 512, (const u16*)nullptr, ht0, 256, 32, 256, 512);
    k_gemm_nt<float, float><<<dim3(4, 1), 256, 0, stream>>>(hFB, 512, cWc, 512, (const u16*)nullptr, ct0, 256, 32, 256, 512);
    // 5. attention projection enc_hiddens @ Watt^T
    k_gemm_nt<u16, u16><<<dim3(4, 256), 256, 0, stream>>>(enc_p, 512, cWatt, 512, (const u16*)nullptr, proj, 256, 16384, 256, 512);
    // 6. embed target + decoder y-part preactivations
    k_embed<<<127 * 32, 256, 0, stream>>>(target, tgt_emb, Yemb, flag);
    k_gemm_nt<u16, float><<<dim3(16, 64), 256, 0, stream>>>(Yemb, 256, cWih_d, 512, cb_d, Ypart, 1024, 4064, 1024, 256);
    // 7. decoder recurrence with attention
    for (int s = 0; s < 127; s++) {
        k_dec_a<<<32, 256, 0, stream>>>(s, Ypart, cWhh_d, cWih_d, ht0, ct0, hdec, cdec, oprev);
        k_dec_b<<<32, 256, 0, stream>>>(s, hdec, proj, enc_p, cWcomb, oprev, hid);
    }
    // 8. scores: logit at target + logsumexp over vocab
    hipMemsetAsync(psum, 0, 4096 * sizeof(float), stream);
    k_lidx<<<(127 * 32 + 3) / 4, 256, 0, stream>>>(target, hid, Wvoc, lidx, flag);
    k_sumexp<<<dim3(250, 127), 256, 0, stream>>>(hid, Wvoc, psum, flag);
    k_scores<<<1, 64, 0, stream>>>(target, lidx, psum, d_out, flag);
}

// Round 5
// 16011.894 us; speedup vs baseline: 1.3976x; 1.3976x over previous
//
#include <hip/hip_runtime.h>
#include <hip/hip_bf16.h>
#include <math.h>

typedef unsigned int u32;
typedef unsigned short u16;

// ---------- bf16 helpers ----------
__device__ __forceinline__ float bfbits(u32 hi) { union { u32 u; float f; } v; v.u = hi; return v.f; }
__device__ __forceinline__ float lo16(u32 p) { return bfbits(p << 16); }
__device__ __forceinline__ float hi16(u32 p) { return bfbits(p & 0xffff0000u); }
__device__ __forceinline__ float b2f(u16 x) { return bfbits(((u32)x) << 16); }
__device__ __forceinline__ u16 f2b(float f) {
    union { float f; u32 u; } v; v.f = f;
    u32 u = v.u;
    u32 r = (u + 0x7fffu + ((u >> 16) & 1u)) >> 16;  // RNE
    return (u16)r;
}
__device__ __forceinline__ float cvtf(float x) { return x; }
__device__ __forceinline__ float cvtf(u16 x) { return b2f(x); }
__device__ __forceinline__ void storef(float* p, float v) { *p = v; }
__device__ __forceinline__ void storef(u16* p, float v) { *p = f2b(v); }
__device__ __forceinline__ float sigf(float x) { return 1.f / (1.f + expf(-x)); }
__device__ __forceinline__ float dot8(uint4 q, const float* h) {
    return lo16(q.x) * h[0] + hi16(q.x) * h[1] + lo16(q.y) * h[2] + hi16(q.y) * h[3]
         + lo16(q.z) * h[4] + hi16(q.z) * h[5] + lo16(q.w) * h[6] + hi16(q.w) * h[7];
}

// ---------- dtype-world detector (unchanged, proven) ----------
__global__ void k_detect(const void* __restrict__ emb, int* __restrict__ flag) {
    __shared__ int s;
    if (threadIdx.x == 0) s = 0;
    __syncthreads();
    const u16* p = (const u16*)emb;
    int bad = 0;
    for (int i = threadIdx.x; i < 8192; i += 256) {
        float v = b2f(p[i]);
        if (!(fabsf(v) < 1e4f)) bad = 1;
    }
    if (bad) s = 1;
    __syncthreads();
    if (threadIdx.x == 0) *flag = s;
}

// ---------- weight canonicalizer ----------
__global__ void k_conv(const void* __restrict__ src, u16* __restrict__ dst, int n,
                       const int* __restrict__ flag) {
    int i = blockIdx.x * 256 + threadIdx.x;
    if (i >= n) return;
    if (*flag) dst[i] = f2b(((const float*)src)[i]);
    else       dst[i] = ((const u16*)src)[i];
}

// ---------- Watt transpose: WattT[c][r] = Watt[r][c], 256x512 -> 512x256 ----------
__global__ void k_wattT(const void* __restrict__ src, u16* __restrict__ dst,
                        const int* __restrict__ flag) {
    int c = blockIdx.x;   // 0..511
    int r = threadIdx.x;  // 0..255
    u16 v;
    if (*flag) v = f2b(((const float*)src)[(size_t)r * 512 + c]);
    else       v = ((const u16*)src)[(size_t)r * 512 + c];
    dst[(size_t)c * 256 + r] = v;
}

// ---------- embedding gather -> internal bf16 ----------
__global__ void k_embed(const int* __restrict__ tok, const void* __restrict__ emb,
                        u16* __restrict__ out, const int* __restrict__ flag) {
    int row = blockIdx.x;
    int e = threadIdx.x;
    int v = tok[row];
    u16 r;
    if (*flag) r = f2b(((const float*)emb)[(size_t)v * 256 + e]);
    else       r = ((const u16*)emb)[(size_t)v * 256 + e];
    out[(size_t)row * 256 + e] = r;
}

// ---------- generic GEMM: C[m][n] = sum_k A[m][k]*B[n][k] (+bias[n]) ----------
template <typename TA, typename TC>
__global__ __launch_bounds__(256) void k_gemm_nt(
    const TA* __restrict__ A, int lda,
    const u16* __restrict__ B, int ldb,
    const u16* __restrict__ bias,
    TC* __restrict__ C, int ldc,
    int M, int N, int K) {
    __shared__ float As[32][68];
    __shared__ float Bs[32][68];
    const int bm = blockIdx.y * 64, bn = blockIdx.x * 64;
    const int tid = threadIdx.x;
    const int tm = (tid & 15) * 4, tn = (tid >> 4) * 4;
    float acc[4][4] = {};
    const int ml = tid >> 2, kl = (tid & 3) * 8;
    for (int k0 = 0; k0 < K; k0 += 32) {
        {
            float v[8];
            if (bm + ml < M) {
                const TA* ap = A + (size_t)(bm + ml) * lda + (k0 + kl);
#pragma unroll
                for (int i = 0; i < 8; i++) v[i] = cvtf(ap[i]);
            } else {
#pragma unroll
                for (int i = 0; i < 8; i++) v[i] = 0.f;
            }
#pragma unroll
            for (int i = 0; i < 8; i++) As[kl + i][ml] = v[i];
        }
        {
            float v[8];
            if (bn + ml < N) {
                const u16* bp = B + (size_t)(bn + ml) * ldb + (k0 + kl);
#pragma unroll
                for (int i = 0; i < 8; i++) v[i] = b2f(bp[i]);
            } else {
#pragma unroll
                for (int i = 0; i < 8; i++) v[i] = 0.f;
            }
#pragma unroll
            for (int i = 0; i < 8; i++) Bs[kl + i][ml] = v[i];
        }
        __syncthreads();
#pragma unroll
        for (int k = 0; k < 32; k++) {
            float4 av = *(const float4*)&As[k][tm];
            float4 bv = *(const float4*)&Bs[k][tn];
            acc[0][0] += av.x * bv.x; acc[0][1] += av.x * bv.y; acc[0][2] += av.x * bv.z; acc[0][3] += av.x * bv.w;
            acc[1][0] += av.y * bv.x; acc[1][1] += av.y * bv.y; acc[1][2] += av.y * bv.z; acc[1][3] += av.y * bv.w;
            acc[2][0] += av.z * bv.x; acc[2][1] += av.z * bv.y; acc[2][2] += av.z * bv.z; acc[2][3] += av.z * bv.w;
            acc[3][0] += av.w * bv.x; acc[3][1] += av.w * bv.y; acc[3][2] += av.w * bv.z; acc[3][3] += av.w * bv.w;
        }
        __syncthreads();
    }
#pragma unroll
    for (int i = 0; i < 4; i++) {
        int m = bm + tm + i;
        if (m >= M) continue;
#pragma unroll
        for (int j = 0; j < 4; j++) {
            int n = bn + tn + j;
            float v = acc[i][j];
            if (bias) v += b2f(bias[n]);
            storef(&C[(size_t)m * ldc + n], v);
        }
    }
}

// ---------- persistent encoder: 64 blocks (dir*32+b) x 512 threads, 512 steps ----------
// Thread t owns gate-rows r0=t, r1=t+512 of Whh (in 128 VGPRs, packed bf16).
// t<256: i(j=t), g(j=t);  t>=256: f(j=t-256), o(j=t-256).  c-state lives in thread j<256.
__global__ __launch_bounds__(512) void k_enc_persist(
    const float* __restrict__ Xf, const float* __restrict__ Xb,
    const u16* __restrict__ Whh_f, const u16* __restrict__ Whh_b,
    u16* __restrict__ enc, float* __restrict__ hFB) {
    const int d = blockIdx.x >> 5, b = blockIdx.x & 31;
    const int t = threadIdx.x;
    const u16* W = d ? Whh_b : Whh_f;
    u32 w0[64], w1[64];
    {
        const uint4* p0 = (const uint4*)(W + (size_t)t * 256);
        const uint4* p1 = (const uint4*)(W + (size_t)(t + 512) * 256);
#pragma unroll
        for (int i = 0; i < 16; i++) {
            *(uint4*)&w0[i * 4] = p0[i];
            *(uint4*)&w1[i * 4] = p1[i];
        }
    }
    __shared__ float hs[256];
    __shared__ float af[256], ao[256];
    float c = 0.f;
    if (t < 256) hs[t] = 0.f;
    __syncthreads();
    const float* Xd = d ? Xb : Xf;
    for (int step = 0; step < 512; step++) {
        const int pos = d ? (511 - step) : step;
        const float* xp = Xd + ((size_t)pos * 32 + b) * 1024;
        float a0 = xp[t], a1 = xp[t + 512];
#pragma unroll
        for (int i = 0; i < 64; i += 2) {
            float4 h4 = *(const float4*)&hs[2 * i];
            a0 += lo16(w0[i]) * h4.x + hi16(w0[i]) * h4.y + lo16(w0[i + 1]) * h4.z + hi16(w0[i + 1]) * h4.w;
            a1 += lo16(w1[i]) * h4.x + hi16(w1[i]) * h4.y + lo16(w1[i + 1]) * h4.z + hi16(w1[i + 1]) * h4.w;
        }
        if (t >= 256) { af[t - 256] = a0; ao[t - 256] = a1; }
        __syncthreads();
        if (t < 256) {
            float ig = sigf(a0), gg = tanhf(a1);
            float fg = sigf(af[t]), og = sigf(ao[t]);
            c = fg * c + ig * gg;
            float h = og * tanhf(c);
            hs[t] = h;
            enc[((size_t)b * 512 + pos) * 512 + (size_t)d * 256 + t] = f2b(h);
        }
        __syncthreads();
    }
    if (t < 256) hFB[(size_t)b * 512 + (size_t)d * 256 + t] = hs[t];
}

// ---------- persistent decoder: 32 blocks (b) x 512 threads, 127 steps ----------
// LSTM: thread t owns rows r0=t, r1=t+512 of Whh_d (regs); o-part of Wih_d streamed.
// Attention: e = enc . (WattT h); softmax; ctx; o_t = tanh(Wcomb [h;ctx]).
__global__ __launch_bounds__(512) void k_dec_persist(
    const float* __restrict__ Ypart,
    const u16* __restrict__ Whh_d, const u16* __restrict__ Wih_d,
    const u16* __restrict__ WattT, const u16* __restrict__ Wcomb,
    const u16* __restrict__ enc,
    const float* __restrict__ ht0, const float* __restrict__ ct0,
    float* __restrict__ hid) {
    const int b = blockIdx.x;
    const int t = threadIdx.x;
    u32 w0[64], w1[64];
    {
        const uint4* p0 = (const uint4*)(Whh_d + (size_t)t * 256);
        const uint4* p1 = (const uint4*)(Whh_d + (size_t)(t + 512) * 256);
#pragma unroll
        for (int i = 0; i < 16; i++) {
            *(uint4*)&w0[i * 4] = p0[i];
            *(uint4*)&w1[i * 4] = p1[i];
        }
    }
    __shared__ float hs[256], os[256];
    __shared__ float af[256], ao2[256];
    __shared__ float g[512], ev[512], cx[512];
    __shared__ float red[12];
    float c = 0.f;
    if (t < 256) {
        hs[t] = ht0[(size_t)b * 256 + t];
        os[t] = 0.f;
        c = ct0[(size_t)b * 256 + t];
    }
    __syncthreads();
    const u32* wo0 = (const u32*)(Wih_d + (size_t)t * 512 + 256);
    const u32* wo1 = (const u32*)(Wih_d + (size_t)(t + 512) * 512 + 256);
    for (int s = 0; s < 127; s++) {
        // ---- LSTM gates ----
        const float* yp = Ypart + ((size_t)s * 32 + b) * 1024;
        float a0 = yp[t], a1 = yp[t + 512];
#pragma unroll
        for (int i = 0; i < 64; i += 2) {
            float4 h4 = *(const float4*)&hs[2 * i];
            a0 += lo16(w0[i]) * h4.x + hi16(w0[i]) * h4.y + lo16(w0[i + 1]) * h4.z + hi16(w0[i + 1]) * h4.w;
            a1 += lo16(w1[i]) * h4.x + hi16(w1[i]) * h4.y + lo16(w1[i + 1]) * h4.z + hi16(w1[i + 1]) * h4.w;
        }
#pragma unroll 8
        for (int i = 0; i < 128; i += 2) {
            float4 o4 = *(const float4*)&os[2 * i];
            u32 qa = wo0[i], qb = wo0[i + 1], qc = wo1[i], qd = wo1[i + 1];
            a0 += lo16(qa) * o4.x + hi16(qa) * o4.y + lo16(qb) * o4.z + hi16(qb) * o4.w;
            a1 += lo16(qc) * o4.x + hi16(qc) * o4.y + lo16(qd) * o4.z + hi16(qd) * o4.w;
        }
        if (t >= 256) { af[t - 256] = a0; ao2[t - 256] = a1; }
        __syncthreads();
        if (t < 256) {
            float ig = sigf(a0), gg = tanhf(a1);
            float fg = sigf(af[t]), og = sigf(ao2[t]);
            c = fg * c + ig * gg;
            float h = og * tanhf(c);
            hs[t] = h;
        }
        __syncthreads();
        // ---- B: g[t] = WattT[t] . h ----
        {
            const u32* wt = (const u32*)(WattT + (size_t)t * 256);
            float a = 0.f;
#pragma unroll 8
            for (int i = 0; i < 128; i += 2) {
                float4 h4 = *(const float4*)&hs[2 * i];
                u32 qa = wt[i], qb = wt[i + 1];
                a += lo16(qa) * h4.x + hi16(qa) * h4.y + lo16(qb) * h4.z + hi16(qb) * h4.w;
            }
            g[t] = a;
        }
        __syncthreads();
        // ---- C: e[t] = enc[b][t][:] . g ----
        float e_own;
        {
            const u32* er = (const u32*)(enc + ((size_t)b * 512 + t) * 512);
            float a = 0.f;
#pragma unroll 8
            for (int i = 0; i < 256; i += 2) {
                float4 g4 = *(const float4*)&g[2 * i];
                u32 qa = er[i], qb = er[i + 1];
                a += lo16(qa) * g4.x + hi16(qa) * g4.y + lo16(qb) * g4.z + hi16(qb) * g4.w;
            }
            e_own = a;
        }
        // ---- softmax over 512 ----
        {
            float m = e_own;
            for (int off = 32; off; off >>= 1) m = fmaxf(m, __shfl_down(m, off));
            if ((t & 63) == 0) red[t >> 6] = m;
        }
        __syncthreads();
        if (t == 0) {
            float mm = red[0];
#pragma unroll
            for (int i = 1; i < 8; i++) mm = fmaxf(mm, red[i]);
            red[8] = mm;
        }
        __syncthreads();
        {
            float p = expf(e_own - red[8]);
            ev[t] = p;
            float ss = p;
            for (int off = 32; off; off >>= 1) ss += __shfl_down(ss, off);
            if ((t & 63) == 0) red[t >> 6] = ss;
        }
        __syncthreads();
        if (t == 0) {
            float s2 = 0.f;
#pragma unroll
            for (int i = 0; i < 8; i++) s2 += red[i];
            red[9] = 1.f / s2;
        }
        __syncthreads();
        // ---- D: ctx[t] = inv * sum_s ev[s] * enc[b][s][t] ----
        {
            float a = 0.f;
            const u16* ec = enc + (size_t)b * 512 * 512 + t;
            for (int s2 = 0; s2 < 512; s2 += 4) {
                float4 a4 = *(const float4*)&ev[s2];
                a += a4.x * b2f(ec[(size_t)s2 * 512]);
                a += a4.y * b2f(ec[(size_t)(s2 + 1) * 512]);
                a += a4.z * b2f(ec[(size_t)(s2 + 2) * 512]);
                a += a4.w * b2f(ec[(size_t)(s2 + 3) * 512]);
            }
            cx[t] = a * red[9];
        }
        __syncthreads();
        // ---- E: o_t partial sums (2 threads per output j) ----
        {
            const int j = t & 255;
            float a = 0.f;
            if (t < 256) {
                const u32* wc = (const u32*)(Wcomb + (size_t)j * 768);
#pragma unroll 8
                for (int i = 0; i < 128; i += 2) {
                    float4 h4 = *(const float4*)&hs[2 * i];
                    u32 qa = wc[i], qb = wc[i + 1];
                    a += lo16(qa) * h4.x + hi16(qa) * h4.y + lo16(qb) * h4.z + hi16(qb) * h4.w;
                }
#pragma unroll 8
                for (int i = 128; i < 192; i += 2) {
                    float4 c4 = *(const float4*)&cx[2 * i - 256];
                    u32 qa = wc[i], qb = wc[i + 1];
                    a += lo16(qa) * c4.x + hi16(qa) * c4.y + lo16(qb) * c4.z + hi16(qb) * c4.w;
                }
            } else {
                const u32* wc = (const u32*)(Wcomb + (size_t)j * 768 + 384);
#pragma unroll 8
                for (int i = 0; i < 192; i += 2) {
                    float4 c4 = *(const float4*)&cx[128 + 2 * i];
                    u32 qa = wc[i], qb = wc[i + 1];
                    a += lo16(qa) * c4.x + hi16(qa) * c4.y + lo16(qb) * c4.z + hi16(qb) * c4.w;
                }
            }
            g[t] = a;  // reuse g as partial-sum buffer
        }
        __syncthreads();
        if (t < 256) {
            float o = tanhf(g[t] + g[t + 256]);
            os[t] = o;
            hid[((size_t)s * 32 + b) * 256 + t] = o;
        }
        __syncthreads();
    }
}

// ---------- logit at target index ----------
__global__ __launch_bounds__(256) void k_lidx(
    const int* __restrict__ target, const float* __restrict__ hid,
    const void* __restrict__ WvocV, float* __restrict__ lidx,
    const int* __restrict__ flag) {
    int p = blockIdx.x * 4 + (threadIdx.x >> 6);
    if (p >= 127 * 32) return;
    int lane = threadIdx.x & 63;
    int t = p >> 5, b = p & 31;
    int idx = target[(t + 1) * 32 + b];
    const float* h = hid + (size_t)p * 256;
    const bool f32w = (*flag != 0);
    float a = 0.f;
#pragma unroll
    for (int i = 0; i < 4; i++) {
        int k = lane * 4 + i;
        float wv = f32w ? ((const float*)WvocV)[(size_t)idx * 256 + k]
                        : b2f(((const u16*)WvocV)[(size_t)idx * 256 + k]);
        a += h[k] * wv;
    }
    for (int off = 32; off; off >>= 1) a += __shfl_down(a, off);
    if (lane == 0) lidx[p] = a;
}

// ---------- fused vocab GEMM + sum(exp(logit)) ----------
__global__ __launch_bounds__(256) void k_sumexp(
    const float* __restrict__ hid, const void* __restrict__ WvocV,
    float* __restrict__ psum, const int* __restrict__ flag) {
    const int t = blockIdx.y;
    const int cb = blockIdx.x * 128;
    const int tid = threadIdx.x;
    const bool f32w = (*flag != 0);
    __shared__ float Hsh[32][260];
    __shared__ float Wsh[32][132];
    __shared__ float red[32][33];
    {
        int r = tid >> 3, kb = (tid & 7) * 32;
        const float4* hp4 = (const float4*)(hid + ((size_t)t * 32 + r) * 256 + kb);
        float4* dst = (float4*)&Hsh[r][kb];
#pragma unroll
        for (int i = 0; i < 8; i++) dst[i] = hp4[i];
    }
    const int rt = tid >> 5, ct = tid & 31;
    float acc[4][4] = {};
    for (int kc = 0; kc < 8; kc++) {
        __syncthreads();
        {
            int c = tid >> 1, half = tid & 1;
            int k0 = half * 16;
            float w[16];
            if (f32w) {
                const float4* wf = (const float4*)((const float*)WvocV + (size_t)(cb + c) * 256 + kc * 32 + half * 16);
                float4 a0 = wf[0], a1 = wf[1], a2 = wf[2], a3 = wf[3];
                w[0] = a0.x; w[1] = a0.y; w[2] = a0.z; w[3] = a0.w;
                w[4] = a1.x; w[5] = a1.y; w[6] = a1.z; w[7] = a1.w;
                w[8] = a2.x; w[9] = a2.y; w[10] = a2.z; w[11] = a2.w;
                w[12] = a3.x; w[13] = a3.y; w[14] = a3.z; w[15] = a3.w;
            } else {
                const uint4* w4 = (const uint4*)((const u16*)WvocV + (size_t)(cb + c) * 256 + kc * 32 + half * 16);
                uint4 q0 = w4[0], q1 = w4[1];
                w[0] = lo16(q0.x); w[1] = hi16(q0.x); w[2] = lo16(q0.y); w[3] = hi16(q0.y);
                w[4] = lo16(q0.z); w[5] = hi16(q0.z); w[6] = lo16(q0.w); w[7] = hi16(q0.w);
                w[8] = lo16(q1.x); w[9] = hi16(q1.x); w[10] = lo16(q1.y); w[11] = hi16(q1.y);
                w[12] = lo16(q1.z); w[13] = hi16(q1.z); w[14] = lo16(q1.w); w[15] = hi16(q1.w);
            }
#pragma unroll
            for (int i = 0; i < 16; i++) Wsh[k0 + i][c] = w[i];
        }
        __syncthreads();
#pragma unroll
        for (int k = 0; k < 32; k++) {
            float4 bv = *(const float4*)&Wsh[k][ct * 4];
            float a0 = Hsh[rt * 4 + 0][kc * 32 + k];
            float a1 = Hsh[rt * 4 + 1][kc * 32 + k];
            float a2 = Hsh[rt * 4 + 2][kc * 32 + k];
            float a3 = Hsh[rt * 4 + 3][kc * 32 + k];
            acc[0][0] += a0 * bv.x; acc[0][1] += a0 * bv.y; acc[0][2] += a0 * bv.z; acc[0][3] += a0 * bv.w;
            acc[1][0] += a1 * bv.x; acc[1][1] += a1 * bv.y; acc[1][2] += a1 * bv.z; acc[1][3] += a1 * bv.w;
            acc[2][0] += a2 * bv.x; acc[2][1] += a2 * bv.y; acc[2][2] += a2 * bv.z; acc[2][3] += a2 * bv.w;
            acc[3][0] += a3 * bv.x; acc[3][1] += a3 * bv.y; acc[3][2] += a3 * bv.z; acc[3][3] += a3 * bv.w;
        }
    }
#pragma unroll
    for (int i = 0; i < 4; i++) {
        float s = expf(acc[i][0]) + expf(acc[i][1]) + expf(acc[i][2]) + expf(acc[i][3]);
        red[rt * 4 + i][ct] = s;
    }
    __syncthreads();
    if (tid < 32) {
        float s = 0.f;
#pragma unroll 8
        for (int c = 0; c < 32; c++) s += red[tid][c];
        atomicAdd(&psum[(size_t)t * 32 + tid], s);
    }
}

// ---------- final scores ----------
__global__ void k_scores(const int* __restrict__ target, const float* __restrict__ lidx,
                         const float* __restrict__ psum, void* __restrict__ outv,
                         const int* __restrict__ flag) {
    int b = threadIdx.x;
    if (b >= 32) return;
    float acc = 0.f;
    for (int t = 0; t < 127; t++) {
        int idx = target[(t + 1) * 32 + b];
        if (idx != 0) {
            int row = t * 32 + b;
            acc += lidx[row] - logf(psum[row]);
        }
    }
    if (*flag) ((float*)outv)[b] = acc;
    else       ((u16*)outv)[b] = f2b(acc);
}

extern "C" void kernel_launch(void* const* d_in, const int* in_sizes, int n_in,
                              void* d_out, int out_size, void* d_ws, size_t ws_size,
                              hipStream_t stream) {
    const int* source = (const int*)d_in[0];
    const int* target = (const int*)d_in[1];
    const void* src_emb = d_in[2];
    const void* tgt_emb = d_in[3];
    const void* Wih_f = d_in[4];
    const void* Whh_f = d_in[5];
    const void* b_f = d_in[6];
    const void* Wih_b = d_in[7];
    const void* Whh_b = d_in[8];
    const void* b_b = d_in[9];
    const void* Wih_d = d_in[10];
    const void* Whh_d = d_in[11];
    const void* b_d = d_in[12];
    const void* Wh = d_in[13];
    const void* Wc = d_in[14];
    const void* Watt = d_in[15];
    const void* Wcomb = d_in[16];
    const void* Wvoc = d_in[17];

    // ---- workspace layout: [flag pad][f32 buffers][u16 buffers] ----
    int* flag = (int*)d_ws;
    float* fw = (float*)d_ws;
    size_t off = 64;
    float* Xf = fw + off;     off += (size_t)512 * 32 * 1024;
    float* Xb = fw + off;     off += (size_t)512 * 32 * 1024;
    float* Ypart = fw + off;  off += (size_t)127 * 32 * 1024;
    float* hid = fw + off;    off += (size_t)127 * 32 * 256;
    float* hFB = fw + off;    off += (size_t)32 * 512;
    float* ht0 = fw + off;    off += (size_t)32 * 256;
    float* ct0 = fw + off;    off += (size_t)32 * 256;
    float* lidx = fw + off;   off += 4096;
    float* psum = fw + off;   off += 4096;
    u16* ub = (u16*)(fw + off);
    size_t uo = 0;
    u16* X = ub + uo;       uo += (size_t)512 * 32 * 256;
    u16* Yemb = ub + uo;    uo += (size_t)127 * 32 * 256;
    u16* enc_p = ub + uo;   uo += (size_t)32 * 512 * 512;
    u16* WattT = ub + uo;   uo += 131072;
    u16* cWih_f = ub + uo;  uo += 262144;
    u16* cWhh_f = ub + uo;  uo += 262144;
    u16* cb_f = ub + uo;    uo += 1024;
    u16* cWih_b = ub + uo;  uo += 262144;
    u16* cWhh_b = ub + uo;  uo += 262144;
    u16* cb_b = ub + uo;    uo += 1024;
    u16* cWih_d = ub + uo;  uo += 524288;
    u16* cWhh_d = ub + uo;  uo += 262144;
    u16* cb_d = ub + uo;    uo += 1024;
    u16* cWh = ub + uo;     uo += 131072;
    u16* cWc = ub + uo;     uo += 131072;
    u16* cWcomb = ub + uo;  uo += 196608;
    size_t needed = off * 4 + uo * 2;
    if (ws_size < needed) return;

    // 0. detect dtype world, canonicalize weights
    k_detect<<<1, 256, 0, stream>>>(src_emb, flag);
    auto conv = [&](const void* s, u16* d, int n) {
        k_conv<<<(n + 255) / 256, 256, 0, stream>>>(s, d, n, flag);
    };
    conv(Wih_f, cWih_f, 262144);  conv(Whh_f, cWhh_f, 262144);  conv(b_f, cb_f, 1024);
    conv(Wih_b, cWih_b, 262144);  conv(Whh_b, cWhh_b, 262144);  conv(b_b, cb_b, 1024);
    conv(Wih_d, cWih_d, 524288);  conv(Whh_d, cWhh_d, 262144);  conv(b_d, cb_d, 1024);
    conv(Wh, cWh, 131072);        conv(Wc, cWc, 131072);
    conv(Wcomb, cWcomb, 196608);
    k_wattT<<<512, 256, 0, stream>>>(Watt, WattT, flag);

    // 1. embed source
    k_embed<<<512 * 32, 256, 0, stream>>>(source, src_emb, X, flag);
    // 2. x-part gate preactivations, both directions
    k_gemm_nt<u16, float><<<dim3(16, 256), 256, 0, stream>>>(X, 256, cWih_f, 256, cb_f, Xf, 1024, 16384, 1024, 256);
    k_gemm_nt<u16, float><<<dim3(16, 256), 256, 0, stream>>>(X, 256, cWih_b, 256, cb_b, Xb, 1024, 16384, 1024, 256);
    // 3. persistent encoder (fwd+bwd, 512 steps, 1 launch)
    k_enc_persist<<<64, 512, 0, stream>>>(Xf, Xb, cWhh_f, cWhh_b, enc_p, hFB);
    // 4. initial decoder state
    k_gemm_nt<float, float><<<dim3(4, 1), 256, 0, stream>>>(hFB, 512, cWh, 512, (const u16*)nullptr, ht0, 256, 32, 256, 512);
    k_gemm_nt<float, float><<<dim3(4, 1), 256, 0, stream>>>(hFB, 512, cWc, 512, (const u16*)nullptr, ct0, 256, 32, 256, 512);
    // 5. embed target + decoder y-part preactivations
    k_embed<<<127 * 32, 256, 0, stream>>>(target, tgt_emb, Yemb, flag);
    k_gemm_nt<u16, float><<<dim3(16, 64), 256, 0, stream>>>(Yemb, 256, cWih_d, 512, cb_d, Ypart, 1024, 4064, 1024, 256);
    // 6. persistent decoder (127 steps with attention, 1 launch)
    k_dec_persist<<<32, 512, 0, stream>>>(Ypart, cWhh_d, cWih_d, WattT, cWcomb, enc_p, ht0, ct0, hid);
    // 7. scores
    hipMemsetAsync(psum, 0, 4096 * sizeof(float), stream);
    k_lidx<<<(127 * 32 + 3) / 4, 256, 0, stream>>>(target, hid, Wvoc, lidx, flag);
    k_sumexp<<<dim3(250, 127), 256, 0, stream>>>(hid, Wvoc, psum, flag);
    k_scores<<<1, 64, 0, stream>>>(target, lidx, psum, d_out, flag);
}